// Round 1
// baseline (295.483 us; speedup 1.0000x reference)
//
#include <hip/hip_runtime.h>
#include <hip/hip_bf16.h>

// Problem constants (B=8, N=256, DIN=DOUT=EIN=EOUT=64)
#define BN   2048      // B*N
#define NN   256       // N
#define CH   64        // channel dims

// ---------------------------------------------------------------------------
// Kernel 1: node_x = emb_node@Wn + bn  (fp32 -> ws)
//           rsx    = relu(emb_node@Wsn + bsn) (fp32 -> ws)
// grid: BN/4 blocks x 256 threads; each thread owns (row, c)
// ---------------------------------------------------------------------------
__global__ __launch_bounds__(256) void node_kernel(
    const float* __restrict__ emb_node, const float* __restrict__ Wn,
    const float* __restrict__ bn, const float* __restrict__ Wsn,
    const float* __restrict__ bsn, float* __restrict__ node_x,
    float* __restrict__ rsx) {
  __shared__ float s_emb[4][CH];
  const int r = threadIdx.x >> 6;
  const int c = threadIdx.x & 63;
  const int row = blockIdx.x * 4 + r;
  s_emb[r][c] = emb_node[row * CH + c];
  __syncthreads();
  float a1 = bn[c], a2 = bsn[c];
#pragma unroll
  for (int k = 0; k < CH; ++k) {
    const float e = s_emb[r][k];                 // wave-uniform LDS broadcast
    a1 = fmaf(e, Wn[k * CH + c], a1);            // coalesced, L2-resident
    a2 = fmaf(e, Wsn[k * CH + c], a2);
  }
  node_x[row * CH + c] = a1;
  rsx[row * CH + c] = fmaxf(a2, 0.0f);
}

// ---------------------------------------------------------------------------
// Kernel 2: per block (b,i):
//   edge_x[j,c] = emb_edge[b,i,j,:]@We[:,c] + be[c]
//   edge_out = relu(edge_x)
//   agg[c]   = sum_j A[b,i,j] * edge_x[j,c] * node_x[b,j,c]
//   node_out[b,i,c] = relu(agg[c]) + rsx[b,i,c]
// 256 threads: c = tid&63 owns one output channel (We column in VGPRs),
// jj = tid>>6 selects the j-subset. emb rows staged 16-at-a-time via float4.
// ---------------------------------------------------------------------------
__global__ __launch_bounds__(256) void edge_kernel(
    const float* __restrict__ A, const float* __restrict__ emb_edge,
    const float* __restrict__ We, const float* __restrict__ be,
    const float* __restrict__ node_x, const float* __restrict__ rsx,
    float* __restrict__ node_out, float* __restrict__ edge_out) {
  const int bi  = blockIdx.x;     // b*N + i
  const int b   = bi >> 8;
  const int tid = threadIdx.x;
  const int c   = tid & 63;
  const int jj  = tid >> 6;       // 0..3

  // We column for this thread's channel -> registers (one-time cost)
  float w[CH];
#pragma unroll
  for (int k = 0; k < CH; ++k) w[k] = We[k * CH + c];
  const float bias = be[c];

  __shared__ float s_emb[16][CH];   // 16 j-rows per staging chunk (4 KB)
  __shared__ float s_A[NN];         // connectivity row (pre-staged)
  __shared__ float s_agg[CH];

  s_A[tid] = A[(size_t)bi * NN + tid];
  if (tid < CH) s_agg[tid] = 0.0f;

  const float* __restrict__ erow = emb_edge + (size_t)bi * NN * CH;
  float* __restrict__ eout       = edge_out + (size_t)bi * NN * CH;
  const float* __restrict__ nx   = node_x + (size_t)b * NN * CH;

  float agg = 0.0f;
  __syncthreads();

  for (int j0 = 0; j0 < NN; j0 += 16) {
    __syncthreads();  // protect s_emb from previous iteration's readers
    // stage 16 rows (16*64 fp32 = 4 KB) with one float4 per thread
    const float4 v = *(const float4*)(erow + j0 * CH + tid * 4);
    *(float4*)(&s_emb[0][0] + tid * 4) = v;
    __syncthreads();
#pragma unroll
    for (int t = 0; t < 4; ++t) {
      const int jl = jj + 4 * t;    // local row 0..15 (whole wave shares jl)
      const int j  = j0 + jl;
      float acc = bias;
#pragma unroll
      for (int k = 0; k < CH; ++k)
        acc = fmaf(s_emb[jl][k], w[k], acc);   // LDS broadcast * VGPR
      eout[j * CH + c] = fmaxf(acc, 0.0f);
      // aggregation uses PRE-relu edge_x (Ae = A * edge_x in the reference)
      agg = fmaf(s_A[j] * acc, nx[j * CH + c], agg);
    }
  }
  atomicAdd(&s_agg[c], agg);   // combine 4 jj-group partials per channel
  __syncthreads();
  if (tid < CH) {
    node_out[(size_t)bi * CH + tid] =
        fmaxf(s_agg[tid], 0.0f) + rsx[(size_t)bi * CH + tid];
  }
}

// ---------------------------------------------------------------------------
extern "C" void kernel_launch(void* const* d_in, const int* in_sizes, int n_in,
                              void* d_out, int out_size, void* d_ws, size_t ws_size,
                              hipStream_t stream) {
  const float* A        = (const float*)d_in[0];  // [8,256,256]
  const float* emb_node = (const float*)d_in[1];  // [8,256,64]
  const float* emb_edge = (const float*)d_in[2];  // [8,256,256,64]
  const float* Wn       = (const float*)d_in[3];  // [64,64]
  const float* bn       = (const float*)d_in[4];  // [64]
  const float* Wsn      = (const float*)d_in[5];  // [64,64]
  const float* bsn      = (const float*)d_in[6];  // [64]
  const float* We       = (const float*)d_in[7];  // [64,64]
  const float* be       = (const float*)d_in[8];  // [64]

  float* node_out = (float*)d_out;                     // [2048,64]
  float* edge_out = (float*)d_out + (size_t)BN * CH;   // [2048,256,64]

  float* node_x = (float*)d_ws;                        // [2048,64] fp32
  float* rsx    = (float*)d_ws + (size_t)BN * CH;      // [2048,64] fp32

  hipLaunchKernelGGL(node_kernel, dim3(BN / 4), dim3(256), 0, stream,
                     emb_node, Wn, bn, Wsn, bsn, node_x, rsx);
  hipLaunchKernelGGL(edge_kernel, dim3(BN), dim3(256), 0, stream,
                     A, emb_edge, We, be, node_x, rsx, node_out, edge_out);
}